// Round 4
// baseline (4024.930 us; speedup 1.0000x reference)
//
#include <hip/hip_runtime.h>
#include <math.h>

// GRUDecoder (NRI decoder) on MI355X — round 4: split-bf16 MFMA everywhere.
// edge kernel (unchanged, proven): relu(U_i+V_j+b1) -> 3-term split-bf16 MFMA
// msg_fc2 -> relu -> *ts -> receiver reduce.
// NEW: gru_kernel (gates + hnew + U,V via MFMA), out_kernel (3-layer MLP via MFMA).

namespace {
constexpr int kB = 16, kT = 40, kTS = 39, kN = 64, kDin = 64, kH = 256;
constexpr int kE = kN * (kN - 1);   // 4032
constexpr int kBN = kB * kN;        // 1024
constexpr int kDout = 64;
}

typedef short short8 __attribute__((ext_vector_type(8)));
typedef float f32x4 __attribute__((ext_vector_type(4)));

__device__ __forceinline__ float sigm(float x) { return 1.f / (1.f + expf(-x)); }

__device__ __forceinline__ unsigned short f2bf(float x) {
    unsigned int u = __float_as_uint(x);
    u = (u + 0x7fffu + ((u >> 16) & 1u)) >> 16;   // RNE
    return (unsigned short)u;
}
__device__ __forceinline__ float bf2f(unsigned short h) {
    return __uint_as_float((unsigned)h << 16);
}
__device__ __forceinline__ void split2(float x, unsigned& h, unsigned& l) {
    unsigned short hv = f2bf(x);
    h = hv;
    l = f2bf(x - bf2f(hv));
}
// split 8 floats -> two uint4 (hi,lo) packed pairs
__device__ __forceinline__ void split8(const float* x, uint4& ph, uint4& pl) {
    unsigned h[8], l[8];
    #pragma unroll
    for (int q = 0; q < 8; ++q) split2(x[q], h[q], l[q]);
    ph.x = h[0] | (h[1] << 16); ph.y = h[2] | (h[3] << 16);
    ph.z = h[4] | (h[5] << 16); ph.w = h[6] | (h[7] << 16);
    pl.x = l[0] | (l[1] << 16); pl.y = l[2] | (l[3] << 16);
    pl.z = l[4] | (l[5] << 16); pl.w = l[6] | (l[7] << 16);
}

// ---------------- setup: edge table, type sums, all weights -> bf16 hi/lo ---
__global__ void setup_kernel(
    const float* __restrict__ rel_rec, const float* __restrict__ rel_send,
    const float* __restrict__ rel_types, const float* __restrict__ W2,
    const float* __restrict__ Whr, const float* __restrict__ Whi,
    const float* __restrict__ Whn, const float* __restrict__ Wir,
    const float* __restrict__ Wii, const float* __restrict__ Win,
    const float* __restrict__ W1,
    const float* __restrict__ bir, const float* __restrict__ bhr,
    const float* __restrict__ bii, const float* __restrict__ bhi,
    const float* __restrict__ fc1w, const float* __restrict__ fc2w,
    const float* __restrict__ fc3w,
    int* __restrict__ edge_at, float* __restrict__ ts,
    unsigned short* __restrict__ W2h, unsigned short* __restrict__ W2l,
    unsigned short* __restrict__ Wrih, unsigned short* __restrict__ Wril,
    unsigned short* __restrict__ Wnhh, unsigned short* __restrict__ Wnhl,
    unsigned short* __restrict__ Wnxh, unsigned short* __restrict__ Wnxl,
    unsigned short* __restrict__ Wuvh, unsigned short* __restrict__ Wuvl,
    unsigned short* __restrict__ F1h, unsigned short* __restrict__ F1l,
    unsigned short* __restrict__ F2h, unsigned short* __restrict__ F2l,
    unsigned short* __restrict__ F3h, unsigned short* __restrict__ F3l,
    float* __restrict__ bri) {
    int idx = blockIdx.x * 256 + threadIdx.x;
    unsigned h, l;
    if (idx < kE) {
        int si = 0, ri = 0;
        for (int n = 0; n < kN; ++n) {
            if (rel_send[idx * kN + n] > 0.5f) si = n;
            if (rel_rec[idx * kN + n] > 0.5f) ri = n;
        }
        edge_at[ri * kN + si] = idx;
    }
    if (idx < kB * kE) ts[idx] = rel_types[2 * idx] + rel_types[2 * idx + 1];
    if (idx < kH * kH) {
        split2(W2[idx], h, l);  W2h[idx] = h;  W2l[idx] = l;
        split2(Whn[idx], h, l); Wnhh[idx] = h; Wnhl[idx] = l;
        split2(fc1w[idx], h, l); F1h[idx] = h; F1l[idx] = l;
        split2(fc2w[idx], h, l); F2h[idx] = h; F2l[idx] = l;
    }
    if (idx < 512 * 320) {  // Wri = [[Whr|Wir],[Whi|Wii]]  rows x K=320
        int row = idx / 320, k = idx - row * 320;
        float v;
        if (row < 256) v = (k < kH) ? Whr[row * kH + k] : Wir[row * kDin + k - kH];
        else { int o = row - 256; v = (k < kH) ? Whi[o * kH + k] : Wii[o * kDin + k - kH]; }
        split2(v, h, l); Wrih[idx] = h; Wril[idx] = l;
    }
    if (idx < kH * kDin) { split2(Win[idx], h, l); Wnxh[idx] = h; Wnxl[idx] = l; }
    if (idx < 512 * 256) {  // Wuv: row<256 -> U (W1 cols 0..255), else V
        int row = idx >> 8, k = idx & 255;
        float v = (row < 256) ? W1[row * 512 + k] : W1[(row - 256) * 512 + 256 + k];
        split2(v, h, l); Wuvh[idx] = h; Wuvl[idx] = l;
    }
    if (idx < kDout * kH) { split2(fc3w[idx], h, l); F3h[idx] = h; F3l[idx] = l; }
    if (idx < 256) bri[idx] = bir[idx] + bhr[idx];
    else if (idx < 512) bri[idx] = bii[idx - 256] + bhi[idx - 256];
}

// ---------------- per-step: edge messages + aggregation (split-bf16 MFMA) --
__global__ __launch_bounds__(256)
void edge_kernel(const float* __restrict__ U, const float* __restrict__ V,
                 const unsigned short* __restrict__ W2h,
                 const unsigned short* __restrict__ W2l,
                 const float* __restrict__ b1, const float* __restrict__ b2,
                 const float* __restrict__ ts, const int* __restrict__ edge_at,
                 float* __restrict__ agg) {
    __shared__ __align__(16) unsigned short h1h[kN * kH];  // 32 KiB, swizzled
    __shared__ __align__(16) unsigned short h1l[kN * kH];  // 32 KiB, swizzled
    __shared__ float vjb[kH];
    __shared__ float tss[kN];
    const int blk = blockIdx.x, b = blk >> 6, j = blk & 63;
    const int tid = threadIdx.x;

    if (tid < kN) {
        int e = edge_at[j * kN + tid];
        tss[tid] = (e < 0) ? 0.f : ts[b * kE + e];
    }
    vjb[tid] = V[(b * kN + j) * kH + tid] + b1[tid];
    __syncthreads();

    {
        const int o = tid & 31, i0 = tid >> 5;
        const int k0 = o * 8;
        const float4 vj0 = *(const float4*)&vjb[k0];
        const float4 vj1 = *(const float4*)&vjb[k0 + 4];
        #pragma unroll
        for (int p = 0; p < 8; ++p) {
            const int i = i0 + 8 * p;
            const float4* up = (const float4*)(U + (b * kN + i) * kH + k0);
            float4 f0 = up[0], f1 = up[1];
            float x[8] = {f0.x + vj0.x, f0.y + vj0.y, f0.z + vj0.z, f0.w + vj0.w,
                          f1.x + vj1.x, f1.y + vj1.y, f1.z + vj1.z, f1.w + vj1.w};
            #pragma unroll
            for (int q = 0; q < 8; ++q) x[q] = (i == j) ? 0.f : fmaxf(x[q], 0.f);
            uint4 ph, pl;
            split8(x, ph, pl);
            const int byte = i * 512 + ((k0 * 2) ^ ((i & 7) << 4));
            *(uint4*)((char*)h1h + byte) = ph;
            *(uint4*)((char*)h1l + byte) = pl;
        }
    }
    __syncthreads();

    const int lane = tid & 63, w = tid >> 6;
    const int mrow = lane & 15, mq = lane >> 4;
    f32x4 acc[4][4];
    #pragma unroll
    for (int mf = 0; mf < 4; ++mf)
        #pragma unroll
        for (int nf = 0; nf < 4; ++nf) acc[mf][nf] = (f32x4){0.f, 0.f, 0.f, 0.f};

    const size_t woff = (size_t)(w * 64 + mrow) * kH + mq * 8;
    const unsigned short* Wph = W2h + woff;
    const unsigned short* Wpl = W2l + woff;
    #pragma unroll
    for (int kt = 0; kt < 8; ++kt) {
        const int k0 = kt * 32;
        short8 ah[4], al[4], bh_[4], bl_[4];
        #pragma unroll
        for (int mf = 0; mf < 4; ++mf) {
            const int r = mf * 16 + mrow;
            const int byte = r * 512 + (((k0 + mq * 8) * 2) ^ ((r & 7) << 4));
            ah[mf] = *(const short8*)((const char*)h1h + byte);
            al[mf] = *(const short8*)((const char*)h1l + byte);
        }
        #pragma unroll
        for (int nf = 0; nf < 4; ++nf) {
            bh_[nf] = *(const short8*)(Wph + nf * 16 * kH + k0);
            bl_[nf] = *(const short8*)(Wpl + nf * 16 * kH + k0);
        }
        #pragma unroll
        for (int mf = 0; mf < 4; ++mf)
            #pragma unroll
            for (int nf = 0; nf < 4; ++nf) {
                acc[mf][nf] = __builtin_amdgcn_mfma_f32_16x16x32_bf16(
                    ah[mf], bh_[nf], acc[mf][nf], 0, 0, 0);
                acc[mf][nf] = __builtin_amdgcn_mfma_f32_16x16x32_bf16(
                    al[mf], bh_[nf], acc[mf][nf], 0, 0, 0);
                acc[mf][nf] = __builtin_amdgcn_mfma_f32_16x16x32_bf16(
                    ah[mf], bl_[nf], acc[mf][nf], 0, 0, 0);
            }
    }

    float tsr[16];
    #pragma unroll
    for (int mf = 0; mf < 4; ++mf)
        #pragma unroll
        for (int r = 0; r < 4; ++r)
            tsr[mf * 4 + r] = tss[mf * 16 + mq * 4 + r];
    #pragma unroll
    for (int nf = 0; nf < 4; ++nf) {
        const int col = w * 64 + nf * 16 + mrow;
        const float bv = b2[col];
        float s = 0.f;
        #pragma unroll
        for (int mf = 0; mf < 4; ++mf)
            #pragma unroll
            for (int r = 0; r < 4; ++r)
                s += tsr[mf * 4 + r] * fmaxf(acc[mf][nf][r] + bv, 0.f);
        s += __shfl_xor(s, 16);
        s += __shfl_xor(s, 32);
        if (lane < 16) agg[(b * kN + j) * kH + col] = s;
    }
}

// ---------------- per-step: GRU gates + hnew + U,V (split-bf16 MFMA) -------
// 32 blocks x 256 thr; block owns 32 rows. Z=[agg|x] K=320 staged hi/lo.
// GEMM1: r,i (Wri, K=320), nh (Wnh, K=256), nx (Wnx, K=64) -> gates in regs.
// GEMM2: hnew (LDS) x Wuv (N=512) -> U,V.
__global__ __launch_bounds__(256, 1)
void gru_kernel(const float* __restrict__ hprev, const float* __restrict__ agg,
                const float* __restrict__ inputs, int t,
                const unsigned short* __restrict__ Wrih, const unsigned short* __restrict__ Wril,
                const unsigned short* __restrict__ Wnhh, const unsigned short* __restrict__ Wnhl,
                const unsigned short* __restrict__ Wnxh, const unsigned short* __restrict__ Wnxl,
                const unsigned short* __restrict__ Wuvh, const unsigned short* __restrict__ Wuvl,
                const float* __restrict__ bri, const float* __restrict__ bhn,
                const float* __restrict__ bin_,
                float* __restrict__ hnew, float* __restrict__ Uo,
                float* __restrict__ Vo) {
    __shared__ __align__(16) unsigned short Zh[32 * 320], Zl[32 * 320];  // 40 KiB
    __shared__ __align__(16) unsigned short Hh[32 * 256], Hl[32 * 256];  // 32 KiB
    const int m0 = blockIdx.x * 32;
    const int tid = threadIdx.x;

    // ---- stage Z = [agg | x], swizzled rows of 640 B
    #pragma unroll
    for (int it = 0; it < 4; ++it) {
        const int c = tid + it * 256;
        const int r = c >> 5, o = c & 31;
        const float* ap = agg + (size_t)(m0 + r) * kH + o * 8;
        float x[8];
        *(float4*)&x[0] = ((const float4*)ap)[0];
        *(float4*)&x[4] = ((const float4*)ap)[1];
        uint4 ph, pl;
        split8(x, ph, pl);
        const int byte = r * 640 + ((o << 4) ^ ((r & 7) << 4));
        *(uint4*)((char*)Zh + byte) = ph;
        *(uint4*)((char*)Zl + byte) = pl;
    }
    {
        const int r = tid >> 3, o = tid & 7;
        const int grow = m0 + r, b = grow >> 6, n = grow & 63;
        const float* xp = inputs + ((size_t)(b * kT + t) * kN + n) * kDin + o * 8;
        float x[8];
        *(float4*)&x[0] = ((const float4*)xp)[0];
        *(float4*)&x[4] = ((const float4*)xp)[1];
        uint4 ph, pl;
        split8(x, ph, pl);
        const int byte = r * 640 + ((512 + (o << 4)) ^ ((r & 7) << 4));
        *(uint4*)((char*)Zh + byte) = ph;
        *(uint4*)((char*)Zl + byte) = pl;
    }
    __syncthreads();

    const int lane = tid & 63, w = tid >> 6;
    const int mrow = lane & 15, mq = lane >> 4;

    f32x4 aR[2][4], aI[2][4], aNH[2][4], aNX[2][4];
    #pragma unroll
    for (int m = 0; m < 2; ++m)
        #pragma unroll
        for (int nf = 0; nf < 4; ++nf) {
            aR[m][nf] = (f32x4){0.f, 0.f, 0.f, 0.f};
            aI[m][nf] = (f32x4){0.f, 0.f, 0.f, 0.f};
            aNH[m][nf] = (f32x4){0.f, 0.f, 0.f, 0.f};
            aNX[m][nf] = (f32x4){0.f, 0.f, 0.f, 0.f};
        }

    #define MFMA3(ACC, ZH, ZL, BH, BL)                                          \
        ACC = __builtin_amdgcn_mfma_f32_16x16x32_bf16(ZH, BH, ACC, 0, 0, 0);    \
        ACC = __builtin_amdgcn_mfma_f32_16x16x32_bf16(ZL, BH, ACC, 0, 0, 0);    \
        ACC = __builtin_amdgcn_mfma_f32_16x16x32_bf16(ZH, BL, ACC, 0, 0, 0);

    #pragma unroll
    for (int kt = 0; kt < 10; ++kt) {
        const int k0 = kt * 32;
        short8 zh[2], zl[2];
        #pragma unroll
        for (int m = 0; m < 2; ++m) {
            const int r = m * 16 + mrow;
            const int byte = r * 640 + (((k0 + mq * 8) * 2) ^ ((r & 7) << 4));
            zh[m] = *(const short8*)((const char*)Zh + byte);
            zl[m] = *(const short8*)((const char*)Zl + byte);
        }
        #pragma unroll
        for (int nf = 0; nf < 4; ++nf) {
            const int row = w * 64 + nf * 16 + mrow;
            {   // r gate
                short8 bh = *(const short8*)(Wrih + (size_t)row * 320 + k0 + mq * 8);
                short8 bl = *(const short8*)(Wril + (size_t)row * 320 + k0 + mq * 8);
                #pragma unroll
                for (int m = 0; m < 2; ++m) { MFMA3(aR[m][nf], zh[m], zl[m], bh, bl); }
            }
            {   // i gate
                short8 bh = *(const short8*)(Wrih + (size_t)(256 + row) * 320 + k0 + mq * 8);
                short8 bl = *(const short8*)(Wril + (size_t)(256 + row) * 320 + k0 + mq * 8);
                #pragma unroll
                for (int m = 0; m < 2; ++m) { MFMA3(aI[m][nf], zh[m], zl[m], bh, bl); }
            }
            if (kt < 8) {   // n gate, h side (agg cols only)
                short8 bh = *(const short8*)(Wnhh + (size_t)row * kH + k0 + mq * 8);
                short8 bl = *(const short8*)(Wnhl + (size_t)row * kH + k0 + mq * 8);
                #pragma unroll
                for (int m = 0; m < 2; ++m) { MFMA3(aNH[m][nf], zh[m], zl[m], bh, bl); }
            } else {        // n gate, x side (x cols)
                short8 bh = *(const short8*)(Wnxh + (size_t)row * kDin + (k0 - 256) + mq * 8);
                short8 bl = *(const short8*)(Wnxl + (size_t)row * kDin + (k0 - 256) + mq * 8);
                #pragma unroll
                for (int m = 0; m < 2; ++m) { MFMA3(aNX[m][nf], zh[m], zl[m], bh, bl); }
            }
        }
    }

    // ---- gates elementwise, hnew -> global + LDS (hi/lo, swizzled)
    #pragma unroll
    for (int m = 0; m < 2; ++m)
        #pragma unroll
        for (int nf = 0; nf < 4; ++nf) {
            const int col = w * 64 + nf * 16 + mrow;
            const float brv = bri[col], biv = bri[256 + col];
            const float bhnv = bhn[col], binv = bin_[col];
            #pragma unroll
            for (int reg = 0; reg < 4; ++reg) {
                const int lr = m * 16 + mq * 4 + reg;
                const int grow = m0 + lr;
                float rg = sigm(aR[m][nf][reg] + brv);
                float ig = sigm(aI[m][nf][reg] + biv);
                float ng = tanhf(aNX[m][nf][reg] + binv + rg * (aNH[m][nf][reg] + bhnv));
                float h2 = (1.f - ig) * ng + ig * hprev[(size_t)grow * kH + col];
                hnew[(size_t)grow * kH + col] = h2;
                unsigned hv, lv;
                split2(h2, hv, lv);
                const int byte = lr * 512 + (((col >> 3) ^ (lr & 7)) << 4) + (col & 7) * 2;
                *(unsigned short*)((char*)Hh + byte) = (unsigned short)hv;
                *(unsigned short*)((char*)Hl + byte) = (unsigned short)lv;
            }
        }
    __syncthreads();

    // ---- GEMM2: U,V = hnew x Wuv^T  (N=512, per wave 128 cols)
    f32x4 aUV[2][8];
    #pragma unroll
    for (int m = 0; m < 2; ++m)
        #pragma unroll
        for (int nf = 0; nf < 8; ++nf) aUV[m][nf] = (f32x4){0.f, 0.f, 0.f, 0.f};
    #pragma unroll
    for (int kt = 0; kt < 8; ++kt) {
        const int k0 = kt * 32;
        short8 zh[2], zl[2];
        #pragma unroll
        for (int m = 0; m < 2; ++m) {
            const int r = m * 16 + mrow;
            const int byte = r * 512 + (((k0 + mq * 8) * 2) ^ ((r & 7) << 4));
            zh[m] = *(const short8*)((const char*)Hh + byte);
            zl[m] = *(const short8*)((const char*)Hl + byte);
        }
        #pragma unroll
        for (int nf = 0; nf < 8; ++nf) {
            const int row = w * 128 + nf * 16 + mrow;
            short8 bh = *(const short8*)(Wuvh + (size_t)row * kH + k0 + mq * 8);
            short8 bl = *(const short8*)(Wuvl + (size_t)row * kH + k0 + mq * 8);
            #pragma unroll
            for (int m = 0; m < 2; ++m) { MFMA3(aUV[m][nf], zh[m], zl[m], bh, bl); }
        }
    }
    #pragma unroll
    for (int m = 0; m < 2; ++m)
        #pragma unroll
        for (int nf = 0; nf < 8; ++nf) {
            const int col = w * 128 + nf * 16 + mrow;
            #pragma unroll
            for (int reg = 0; reg < 4; ++reg) {
                const int grow = m0 + m * 16 + mq * 4 + reg;
                const float v = aUV[m][nf][reg];
                if (col < 256) Uo[(size_t)grow * kH + col] = v;
                else Vo[(size_t)grow * kH + col - 256] = v;
            }
        }
    #undef MFMA3
}

// ---------------- batched output MLP (split-bf16 MFMA) ----------------
// 1248 blocks x 256 thr; block owns 32 rows of the 39936-row hidden history.
__global__ __launch_bounds__(256)
void out_kernel(const float* __restrict__ hist,
                const unsigned short* __restrict__ F1h, const unsigned short* __restrict__ F1l,
                const unsigned short* __restrict__ F2h, const unsigned short* __restrict__ F2l,
                const unsigned short* __restrict__ F3h, const unsigned short* __restrict__ F3l,
                const float* __restrict__ fc1b, const float* __restrict__ fc2b,
                const float* __restrict__ fc3b, float* __restrict__ out) {
    __shared__ __align__(16) unsigned short Ah[32 * 256], Al[32 * 256];  // 32 KiB
    __shared__ __align__(16) unsigned short Bh[32 * 256], Bl[32 * 256];  // 32 KiB
    const int m0 = blockIdx.x * 32;
    const int tid = threadIdx.x;

    #pragma unroll
    for (int it = 0; it < 4; ++it) {
        const int c = tid + it * 256;
        const int r = c >> 5, o = c & 31;
        const float* ap = hist + (size_t)(m0 + r) * kH + o * 8;
        float x[8];
        *(float4*)&x[0] = ((const float4*)ap)[0];
        *(float4*)&x[4] = ((const float4*)ap)[1];
        uint4 ph, pl;
        split8(x, ph, pl);
        const int byte = r * 512 + ((o << 4) ^ ((r & 7) << 4));
        *(uint4*)((char*)Ah + byte) = ph;
        *(uint4*)((char*)Al + byte) = pl;
    }
    __syncthreads();

    const int lane = tid & 63, w = tid >> 6;
    const int mrow = lane & 15, mq = lane >> 4;

    #define MFMA3(ACC, ZH, ZL, BH, BL)                                          \
        ACC = __builtin_amdgcn_mfma_f32_16x16x32_bf16(ZH, BH, ACC, 0, 0, 0);    \
        ACC = __builtin_amdgcn_mfma_f32_16x16x32_bf16(ZL, BH, ACC, 0, 0, 0);    \
        ACC = __builtin_amdgcn_mfma_f32_16x16x32_bf16(ZH, BL, ACC, 0, 0, 0);

    // helper macro: one 256->256 layer from LDS (SRCH/SRCL) to LDS (DSTH/DSTL)
    #define LAYER(SRCH, SRCL, WH, WL, BIAS, DSTH, DSTL)                         \
    {                                                                           \
        f32x4 acc[2][4];                                                        \
        _Pragma("unroll")                                                       \
        for (int m = 0; m < 2; ++m)                                             \
            _Pragma("unroll")                                                   \
            for (int nf = 0; nf < 4; ++nf) acc[m][nf] = (f32x4){0.f,0.f,0.f,0.f};\
        _Pragma("unroll")                                                       \
        for (int kt = 0; kt < 8; ++kt) {                                        \
            const int k0 = kt * 32;                                             \
            short8 zh[2], zl[2];                                                \
            _Pragma("unroll")                                                   \
            for (int m = 0; m < 2; ++m) {                                       \
                const int r = m * 16 + mrow;                                    \
                const int byte = r * 512 + (((k0 + mq * 8) * 2) ^ ((r & 7) << 4)); \
                zh[m] = *(const short8*)((const char*)SRCH + byte);             \
                zl[m] = *(const short8*)((const char*)SRCL + byte);             \
            }                                                                   \
            _Pragma("unroll")                                                   \
            for (int nf = 0; nf < 4; ++nf) {                                    \
                const int row = w * 64 + nf * 16 + mrow;                        \
                short8 bh = *(const short8*)(WH + (size_t)row * kH + k0 + mq * 8); \
                short8 bl = *(const short8*)(WL + (size_t)row * kH + k0 + mq * 8); \
                _Pragma("unroll")                                               \
                for (int m = 0; m < 2; ++m) { MFMA3(acc[m][nf], zh[m], zl[m], bh, bl); } \
            }                                                                   \
        }                                                                       \
        _Pragma("unroll")                                                       \
        for (int m = 0; m < 2; ++m)                                             \
            _Pragma("unroll")                                                   \
            for (int nf = 0; nf < 4; ++nf) {                                    \
                const int col = w * 64 + nf * 16 + mrow;                        \
                const float bv = BIAS[col];                                     \
                _Pragma("unroll")                                               \
                for (int reg = 0; reg < 4; ++reg) {                             \
                    const int lr = m * 16 + mq * 4 + reg;                       \
                    float v = fmaxf(acc[m][nf][reg] + bv, 0.f);                 \
                    unsigned hv, lv;                                            \
                    split2(v, hv, lv);                                          \
                    const int byte = lr * 512 + (((col >> 3) ^ (lr & 7)) << 4) + (col & 7) * 2; \
                    *(unsigned short*)((char*)DSTH + byte) = (unsigned short)hv; \
                    *(unsigned short*)((char*)DSTL + byte) = (unsigned short)lv; \
                }                                                               \
            }                                                                   \
        __syncthreads();                                                        \
    }

    LAYER(Ah, Al, F1h, F1l, fc1b, Bh, Bl)
    LAYER(Bh, Bl, F2h, F2l, fc2b, Ah, Al)

    // fc3: N=64, per wave 1 frag of 16 cols
    {
        f32x4 acc[2];
        acc[0] = (f32x4){0.f, 0.f, 0.f, 0.f};
        acc[1] = (f32x4){0.f, 0.f, 0.f, 0.f};
        const int row = w * 16 + mrow;
        #pragma unroll
        for (int kt = 0; kt < 8; ++kt) {
            const int k0 = kt * 32;
            short8 zh[2], zl[2];
            #pragma unroll
            for (int m = 0; m < 2; ++m) {
                const int r = m * 16 + mrow;
                const int byte = r * 512 + (((k0 + mq * 8) * 2) ^ ((r & 7) << 4));
                zh[m] = *(const short8*)((const char*)Ah + byte);
                zl[m] = *(const short8*)((const char*)Al + byte);
            }
            short8 bh = *(const short8*)(F3h + (size_t)row * kH + k0 + mq * 8);
            short8 bl = *(const short8*)(F3l + (size_t)row * kH + k0 + mq * 8);
            #pragma unroll
            for (int m = 0; m < 2; ++m) { MFMA3(acc[m], zh[m], zl[m], bh, bl); }
        }
        const int col = w * 16 + mrow;
        const float bv = fc3b[col];
        #pragma unroll
        for (int m = 0; m < 2; ++m)
            #pragma unroll
            for (int reg = 0; reg < 4; ++reg) {
                const int grow = m0 + m * 16 + mq * 4 + reg;
                const int t = grow >> 10, bn = grow & 1023, b = bn >> 6, n = bn & 63;
                out[(((size_t)b * kTS + t) * kN + n) * kDout + col] = acc[m][reg] + bv;
            }
    }
    #undef LAYER
    #undef MFMA3
}

extern "C" void kernel_launch(void* const* d_in, const int* in_sizes, int n_in,
                              void* d_out, int out_size, void* d_ws, size_t ws_size,
                              hipStream_t stream) {
    const float* inputs    = (const float*)d_in[0];
    const float* rel_rec   = (const float*)d_in[1];
    const float* rel_send  = (const float*)d_in[2];
    const float* rel_types = (const float*)d_in[3];
    const float* W1  = (const float*)d_in[4];  const float* b1  = (const float*)d_in[5];
    const float* W2  = (const float*)d_in[6];  const float* b2  = (const float*)d_in[7];
    const float* Wir = (const float*)d_in[8];  const float* bir = (const float*)d_in[9];
    const float* Whr = (const float*)d_in[10]; const float* bhr = (const float*)d_in[11];
    const float* Wii = (const float*)d_in[12]; const float* bii = (const float*)d_in[13];
    const float* Whi = (const float*)d_in[14]; const float* bhi = (const float*)d_in[15];
    const float* Win = (const float*)d_in[16]; const float* bin_ = (const float*)d_in[17];
    const float* Whn = (const float*)d_in[18]; const float* bhn = (const float*)d_in[19];
    const float* fc1w = (const float*)d_in[20]; const float* fc1b = (const float*)d_in[21];
    const float* fc2w = (const float*)d_in[22]; const float* fc2b = (const float*)d_in[23];
    const float* fc3w = (const float*)d_in[24]; const float* fc3b = (const float*)d_in[25];
    float* out = (float*)d_out;

    char* w = (char*)d_ws;
    auto take = [&](size_t bytes) { char* p = w; w += (bytes + 255) & ~(size_t)255; return p; };
    int* edge_at = (int*)take(kN * kN * 4);
    float* ts = (float*)take(kB * kE * 4);
    unsigned short* W2h = (unsigned short*)take(kH * kH * 2);
    unsigned short* W2l = (unsigned short*)take(kH * kH * 2);
    unsigned short* Wrih = (unsigned short*)take(512 * 320 * 2);
    unsigned short* Wril = (unsigned short*)take(512 * 320 * 2);
    unsigned short* Wnhh = (unsigned short*)take(kH * kH * 2);
    unsigned short* Wnhl = (unsigned short*)take(kH * kH * 2);
    unsigned short* Wnxh = (unsigned short*)take(kH * kDin * 2);
    unsigned short* Wnxl = (unsigned short*)take(kH * kDin * 2);
    unsigned short* Wuvh = (unsigned short*)take(512 * 256 * 2);
    unsigned short* Wuvl = (unsigned short*)take(512 * 256 * 2);
    unsigned short* F1h = (unsigned short*)take(kH * kH * 2);
    unsigned short* F1l = (unsigned short*)take(kH * kH * 2);
    unsigned short* F2h = (unsigned short*)take(kH * kH * 2);
    unsigned short* F2l = (unsigned short*)take(kH * kH * 2);
    unsigned short* F3h = (unsigned short*)take(kDout * kH * 2);
    unsigned short* F3l = (unsigned short*)take(kDout * kH * 2);
    float* bri = (float*)take(512 * 4);
    float* U = (float*)take((size_t)kBN * kH * 4);
    float* V = (float*)take((size_t)kBN * kH * 4);
    float* agg = (float*)take((size_t)kBN * kH * 4);
    float* hh = (float*)w;   // (kTS+1) * kBN * kH floats (~42 MiB)

    hipMemsetAsync(edge_at, 0xFF, kN * kN * 4, stream);
    setup_kernel<<<640, 256, 0, stream>>>(
        rel_rec, rel_send, rel_types, W2, Whr, Whi, Whn, Wir, Wii, Win, W1,
        bir, bhr, bii, bhi, fc1w, fc2w, fc3w,
        edge_at, ts, W2h, W2l, Wrih, Wril, Wnhh, Wnhl, Wnxh, Wnxl,
        Wuvh, Wuvl, F1h, F1l, F2h, F2l, F3h, F3l, bri);
    hipMemsetAsync(U, 0, (size_t)kBN * kH * 4, stream);
    hipMemsetAsync(V, 0, (size_t)kBN * kH * 4, stream);
    hipMemsetAsync(hh, 0, (size_t)kBN * kH * 4, stream);   // h_0 = 0

    for (int t = 0; t < kTS; ++t) {
        edge_kernel<<<kBN, 256, 0, stream>>>(U, V, W2h, W2l, b1, b2, ts, edge_at, agg);
        gru_kernel<<<kBN / 32, 256, 0, stream>>>(
            hh + (size_t)t * kBN * kH, agg, inputs, t,
            Wrih, Wril, Wnhh, Wnhl, Wnxh, Wnxl, Wuvh, Wuvl, bri, bhn, bin_,
            hh + (size_t)(t + 1) * kBN * kH, U, V);
    }
    out_kernel<<<kTS * kBN / 32, 256, 0, stream>>>(
        hh + (size_t)kBN * kH, F1h, F1l, F2h, F2l, F3h, F3l,
        fc1b, fc2b, fc3b, out);
}

// Round 5
// 3665.567 us; speedup vs baseline: 1.0980x; 1.0980x over previous
//
#include <hip/hip_runtime.h>
#include <math.h>

// GRUDecoder (NRI decoder) on MI355X — round 5: latency-stall fix.
// Same split-bf16 3-term MFMA math as round 4 (passed, absmax 9.8e-4), plus:
//  - __launch_bounds__ freeing VGPRs (88 -> ~200) for load pipelining
//  - explicit ring-2 prefetch of weight (B) fragments ahead of each MFMA phase
//  - gru_kernel: 64 blocks x 16 rows, nf-outer with per-nf gate epilogue

namespace {
constexpr int kB = 16, kT = 40, kTS = 39, kN = 64, kDin = 64, kH = 256;
constexpr int kE = kN * (kN - 1);   // 4032
constexpr int kBN = kB * kN;        // 1024
constexpr int kDout = 64;
}

typedef short short8 __attribute__((ext_vector_type(8)));
typedef float f32x4 __attribute__((ext_vector_type(4)));

__device__ __forceinline__ float sigm(float x) { return 1.f / (1.f + expf(-x)); }

__device__ __forceinline__ unsigned short f2bf(float x) {
    unsigned int u = __float_as_uint(x);
    u = (u + 0x7fffu + ((u >> 16) & 1u)) >> 16;   // RNE
    return (unsigned short)u;
}
__device__ __forceinline__ float bf2f(unsigned short h) {
    return __uint_as_float((unsigned)h << 16);
}
__device__ __forceinline__ void split2(float x, unsigned& h, unsigned& l) {
    unsigned short hv = f2bf(x);
    h = hv;
    l = f2bf(x - bf2f(hv));
}
__device__ __forceinline__ void split8(const float* x, uint4& ph, uint4& pl) {
    unsigned h[8], l[8];
    #pragma unroll
    for (int q = 0; q < 8; ++q) split2(x[q], h[q], l[q]);
    ph.x = h[0] | (h[1] << 16); ph.y = h[2] | (h[3] << 16);
    ph.z = h[4] | (h[5] << 16); ph.w = h[6] | (h[7] << 16);
    pl.x = l[0] | (l[1] << 16); pl.y = l[2] | (l[3] << 16);
    pl.z = l[4] | (l[5] << 16); pl.w = l[6] | (l[7] << 16);
}

#define MFMA3(ACC, ZH, ZL, BH, BL)                                          \
    ACC = __builtin_amdgcn_mfma_f32_16x16x32_bf16(ZH, BH, ACC, 0, 0, 0);    \
    ACC = __builtin_amdgcn_mfma_f32_16x16x32_bf16(ZL, BH, ACC, 0, 0, 0);    \
    ACC = __builtin_amdgcn_mfma_f32_16x16x32_bf16(ZH, BL, ACC, 0, 0, 0);

// ---------------- setup: edge table, type sums, all weights -> bf16 hi/lo ---
__global__ void setup_kernel(
    const float* __restrict__ rel_rec, const float* __restrict__ rel_send,
    const float* __restrict__ rel_types, const float* __restrict__ W2,
    const float* __restrict__ Whr, const float* __restrict__ Whi,
    const float* __restrict__ Whn, const float* __restrict__ Wir,
    const float* __restrict__ Wii, const float* __restrict__ Win,
    const float* __restrict__ W1,
    const float* __restrict__ bir, const float* __restrict__ bhr,
    const float* __restrict__ bii, const float* __restrict__ bhi,
    const float* __restrict__ fc1w, const float* __restrict__ fc2w,
    const float* __restrict__ fc3w,
    int* __restrict__ edge_at, float* __restrict__ ts,
    unsigned short* __restrict__ W2h, unsigned short* __restrict__ W2l,
    unsigned short* __restrict__ Wrih, unsigned short* __restrict__ Wril,
    unsigned short* __restrict__ Wnhh, unsigned short* __restrict__ Wnhl,
    unsigned short* __restrict__ Wnxh, unsigned short* __restrict__ Wnxl,
    unsigned short* __restrict__ Wuvh, unsigned short* __restrict__ Wuvl,
    unsigned short* __restrict__ F1h, unsigned short* __restrict__ F1l,
    unsigned short* __restrict__ F2h, unsigned short* __restrict__ F2l,
    unsigned short* __restrict__ F3h, unsigned short* __restrict__ F3l,
    float* __restrict__ bri) {
    int idx = blockIdx.x * 256 + threadIdx.x;
    unsigned h, l;
    if (idx < kE) {
        int si = 0, ri = 0;
        for (int n = 0; n < kN; ++n) {
            if (rel_send[idx * kN + n] > 0.5f) si = n;
            if (rel_rec[idx * kN + n] > 0.5f) ri = n;
        }
        edge_at[ri * kN + si] = idx;
    }
    if (idx < kB * kE) ts[idx] = rel_types[2 * idx] + rel_types[2 * idx + 1];
    if (idx < kH * kH) {
        split2(W2[idx], h, l);  W2h[idx] = h;  W2l[idx] = l;
        split2(Whn[idx], h, l); Wnhh[idx] = h; Wnhl[idx] = l;
        split2(fc1w[idx], h, l); F1h[idx] = h; F1l[idx] = l;
        split2(fc2w[idx], h, l); F2h[idx] = h; F2l[idx] = l;
    }
    if (idx < 512 * 320) {  // Wri = [[Whr|Wir],[Whi|Wii]]  rows x K=320
        int row = idx / 320, k = idx - row * 320;
        float v;
        if (row < 256) v = (k < kH) ? Whr[row * kH + k] : Wir[row * kDin + k - kH];
        else { int o = row - 256; v = (k < kH) ? Whi[o * kH + k] : Wii[o * kDin + k - kH]; }
        split2(v, h, l); Wrih[idx] = h; Wril[idx] = l;
    }
    if (idx < kH * kDin) { split2(Win[idx], h, l); Wnxh[idx] = h; Wnxl[idx] = l; }
    if (idx < 512 * 256) {  // Wuv: row<256 -> U (W1 cols 0..255), else V
        int row = idx >> 8, k = idx & 255;
        float v = (row < 256) ? W1[row * 512 + k] : W1[(row - 256) * 512 + 256 + k];
        split2(v, h, l); Wuvh[idx] = h; Wuvl[idx] = l;
    }
    if (idx < kDout * kH) { split2(fc3w[idx], h, l); F3h[idx] = h; F3l[idx] = l; }
    if (idx < 256) bri[idx] = bir[idx] + bhr[idx];
    else if (idx < 512) bri[idx] = bii[idx - 256] + bhi[idx - 256];
}

// ---------------- per-step: edge messages + aggregation (split-bf16 MFMA) --
__global__ __launch_bounds__(256, 2)
void edge_kernel(const float* __restrict__ U, const float* __restrict__ V,
                 const unsigned short* __restrict__ W2h,
                 const unsigned short* __restrict__ W2l,
                 const float* __restrict__ b1, const float* __restrict__ b2,
                 const float* __restrict__ ts, const int* __restrict__ edge_at,
                 float* __restrict__ agg) {
    __shared__ __align__(16) unsigned short h1h[kN * kH];  // 32 KiB, swizzled
    __shared__ __align__(16) unsigned short h1l[kN * kH];  // 32 KiB, swizzled
    __shared__ float vjb[kH];
    __shared__ float tss[kN];
    const int blk = blockIdx.x, b = blk >> 6, j = blk & 63;
    const int tid = threadIdx.x;

    if (tid < kN) {
        int e = edge_at[j * kN + tid];
        tss[tid] = (e < 0) ? 0.f : ts[b * kE + e];
    }
    vjb[tid] = V[(b * kN + j) * kH + tid] + b1[tid];
    __syncthreads();

    {
        const int o = tid & 31, i0 = tid >> 5;
        const int k0 = o * 8;
        const float4 vj0 = *(const float4*)&vjb[k0];
        const float4 vj1 = *(const float4*)&vjb[k0 + 4];
        #pragma unroll
        for (int p = 0; p < 8; ++p) {
            const int i = i0 + 8 * p;
            const float4* up = (const float4*)(U + (b * kN + i) * kH + k0);
            float4 f0 = up[0], f1 = up[1];
            float x[8] = {f0.x + vj0.x, f0.y + vj0.y, f0.z + vj0.z, f0.w + vj0.w,
                          f1.x + vj1.x, f1.y + vj1.y, f1.z + vj1.z, f1.w + vj1.w};
            #pragma unroll
            for (int q = 0; q < 8; ++q) x[q] = (i == j) ? 0.f : fmaxf(x[q], 0.f);
            uint4 ph, pl;
            split8(x, ph, pl);
            const int byte = i * 512 + ((k0 * 2) ^ ((i & 7) << 4));
            *(uint4*)((char*)h1h + byte) = ph;
            *(uint4*)((char*)h1l + byte) = pl;
        }
    }
    __syncthreads();

    const int lane = tid & 63, w = tid >> 6;
    const int mrow = lane & 15, mq = lane >> 4;
    f32x4 acc[4][4];
    #pragma unroll
    for (int mf = 0; mf < 4; ++mf)
        #pragma unroll
        for (int nf = 0; nf < 4; ++nf) acc[mf][nf] = (f32x4){0.f, 0.f, 0.f, 0.f};

    const size_t woff = (size_t)(w * 64 + mrow) * kH + mq * 8;
    const unsigned short* Wph = W2h + woff;
    const unsigned short* Wpl = W2l + woff;

    // ring-2 prefetch of B fragments (8 loads/kt issued one kt ahead)
    short8 rbh[2][4], rbl[2][4];
    #pragma unroll
    for (int nf = 0; nf < 4; ++nf) {
        rbh[0][nf] = *(const short8*)(Wph + nf * 16 * kH);
        rbl[0][nf] = *(const short8*)(Wpl + nf * 16 * kH);
    }
    #pragma unroll
    for (int kt = 0; kt < 8; ++kt) {
        const int cur = kt & 1;
        if (kt + 1 < 8) {
            #pragma unroll
            for (int nf = 0; nf < 4; ++nf) {
                rbh[cur ^ 1][nf] = *(const short8*)(Wph + nf * 16 * kH + (kt + 1) * 32);
                rbl[cur ^ 1][nf] = *(const short8*)(Wpl + nf * 16 * kH + (kt + 1) * 32);
            }
        }
        const int k0 = kt * 32;
        short8 ah[4], al[4];
        #pragma unroll
        for (int mf = 0; mf < 4; ++mf) {
            const int r = mf * 16 + mrow;
            const int byte = r * 512 + (((k0 + mq * 8) * 2) ^ ((r & 7) << 4));
            ah[mf] = *(const short8*)((const char*)h1h + byte);
            al[mf] = *(const short8*)((const char*)h1l + byte);
        }
        #pragma unroll
        for (int mf = 0; mf < 4; ++mf)
            #pragma unroll
            for (int nf = 0; nf < 4; ++nf) {
                MFMA3(acc[mf][nf], ah[mf], al[mf], rbh[cur][nf], rbl[cur][nf]);
            }
    }

    float tsr[16];
    #pragma unroll
    for (int mf = 0; mf < 4; ++mf)
        #pragma unroll
        for (int r = 0; r < 4; ++r)
            tsr[mf * 4 + r] = tss[mf * 16 + mq * 4 + r];
    #pragma unroll
    for (int nf = 0; nf < 4; ++nf) {
        const int col = w * 64 + nf * 16 + mrow;
        const float bv = b2[col];
        float s = 0.f;
        #pragma unroll
        for (int mf = 0; mf < 4; ++mf)
            #pragma unroll
            for (int r = 0; r < 4; ++r)
                s += tsr[mf * 4 + r] * fmaxf(acc[mf][nf][r] + bv, 0.f);
        s += __shfl_xor(s, 16);
        s += __shfl_xor(s, 32);
        if (lane < 16) agg[(b * kN + j) * kH + col] = s;
    }
}

// ---------------- per-step: GRU gates + hnew + U,V (split-bf16 MFMA) -------
// 64 blocks x 256 thr; block owns 16 rows. Z=[agg|x] K=320 staged hi/lo.
// nf-outer loops with ring-2 weight prefetch; per-nf gate epilogue.
__global__ __launch_bounds__(256, 1)
void gru_kernel(const float* __restrict__ hprev, const float* __restrict__ agg,
                const float* __restrict__ inputs, int t,
                const unsigned short* __restrict__ Wrih, const unsigned short* __restrict__ Wril,
                const unsigned short* __restrict__ Wnhh, const unsigned short* __restrict__ Wnhl,
                const unsigned short* __restrict__ Wnxh, const unsigned short* __restrict__ Wnxl,
                const unsigned short* __restrict__ Wuvh, const unsigned short* __restrict__ Wuvl,
                const float* __restrict__ bri, const float* __restrict__ bhn,
                const float* __restrict__ bin_,
                float* __restrict__ hnew, float* __restrict__ Uo,
                float* __restrict__ Vo) {
    __shared__ __align__(16) unsigned short Zh[16 * 320], Zl[16 * 320];  // 20 KiB
    __shared__ __align__(16) unsigned short Hh[16 * 256], Hl[16 * 256];  // 16 KiB
    const int m0 = blockIdx.x * 16;
    const int tid = threadIdx.x;

    // ---- stage Z = [agg | x]: 16 rows x 40 octets, swizzled rows of 640 B
    for (int c = tid; c < 16 * 40; c += 256) {
        const int r = c / 40, g = c - r * 40;
        float x[8];
        if (g < 32) {
            const float* ap = agg + (size_t)(m0 + r) * kH + g * 8;
            *(float4*)&x[0] = ((const float4*)ap)[0];
            *(float4*)&x[4] = ((const float4*)ap)[1];
        } else {
            const int grow = m0 + r, b = grow >> 6, n = grow & 63;
            const float* xp = inputs + ((size_t)(b * kT + t) * kN + n) * kDin + (g - 32) * 8;
            *(float4*)&x[0] = ((const float4*)xp)[0];
            *(float4*)&x[4] = ((const float4*)xp)[1];
        }
        uint4 ph, pl;
        split8(x, ph, pl);
        const int byte = r * 640 + ((g ^ (r & 7)) << 4);
        *(uint4*)((char*)Zh + byte) = ph;
        *(uint4*)((char*)Zl + byte) = pl;
    }
    __syncthreads();

    const int lane = tid & 63, w = tid >> 6;
    const int mrow = lane & 15, mq = lane >> 4;

    // ---- GEMM1 per nf: r,i (K=320), n (h-side K=256, x-side K=64)
    #pragma unroll
    for (int nf = 0; nf < 4; ++nf) {
        const int col = w * 64 + nf * 16 + mrow;
        const unsigned short* WRh = Wrih + (size_t)col * 320 + mq * 8;
        const unsigned short* WRl = Wril + (size_t)col * 320 + mq * 8;
        const unsigned short* WIh = Wrih + (size_t)(256 + col) * 320 + mq * 8;
        const unsigned short* WIl = Wril + (size_t)(256 + col) * 320 + mq * 8;
        const unsigned short* WNhh_ = Wnhh + (size_t)col * kH + mq * 8;
        const unsigned short* WNhl_ = Wnhl + (size_t)col * kH + mq * 8;
        const unsigned short* WNxh_ = Wnxh + (size_t)col * kDin + mq * 8;
        const unsigned short* WNxl_ = Wnxl + (size_t)col * kDin + mq * 8;

        f32x4 aR = {0.f,0.f,0.f,0.f}, aI = {0.f,0.f,0.f,0.f};
        f32x4 aNH = {0.f,0.f,0.f,0.f}, aNX = {0.f,0.f,0.f,0.f};

        short8 rh[2][3], rl[2][3];   // [slot][gate: r,i,n]
        rh[0][0] = *(const short8*)(WRh); rl[0][0] = *(const short8*)(WRl);
        rh[0][1] = *(const short8*)(WIh); rl[0][1] = *(const short8*)(WIl);
        rh[0][2] = *(const short8*)(WNhh_); rl[0][2] = *(const short8*)(WNhl_);
        #pragma unroll
        for (int kt = 0; kt < 10; ++kt) {
            const int cur = kt & 1;
            if (kt + 1 < 10) {
                const int k1 = (kt + 1) * 32;
                rh[cur^1][0] = *(const short8*)(WRh + k1); rl[cur^1][0] = *(const short8*)(WRl + k1);
                rh[cur^1][1] = *(const short8*)(WIh + k1); rl[cur^1][1] = *(const short8*)(WIl + k1);
                if (kt + 1 < 8) {
                    rh[cur^1][2] = *(const short8*)(WNhh_ + k1);
                    rl[cur^1][2] = *(const short8*)(WNhl_ + k1);
                } else {
                    rh[cur^1][2] = *(const short8*)(WNxh_ + (k1 - 256));
                    rl[cur^1][2] = *(const short8*)(WNxl_ + (k1 - 256));
                }
            }
            const int g = kt * 4 + mq;
            const int byte = mrow * 640 + ((g ^ (mrow & 7)) << 4);
            short8 zh = *(const short8*)((const char*)Zh + byte);
            short8 zl = *(const short8*)((const char*)Zl + byte);
            MFMA3(aR, zh, zl, rh[cur][0], rl[cur][0]);
            MFMA3(aI, zh, zl, rh[cur][1], rl[cur][1]);
            if (kt < 8) { MFMA3(aNH, zh, zl, rh[cur][2], rl[cur][2]); }
            else        { MFMA3(aNX, zh, zl, rh[cur][2], rl[cur][2]); }
        }

        // gate elementwise for this nf's 16 cols
        const float brv = bri[col], biv = bri[256 + col];
        const float bhnv = bhn[col], binv = bin_[col];
        #pragma unroll
        for (int reg = 0; reg < 4; ++reg) {
            const int lr = mq * 4 + reg;
            const int grow = m0 + lr;
            float rg = sigm(aR[reg] + brv);
            float ig = sigm(aI[reg] + biv);
            float ng = tanhf(aNX[reg] + binv + rg * (aNH[reg] + bhnv));
            float h2 = (1.f - ig) * ng + ig * hprev[(size_t)grow * kH + col];
            hnew[(size_t)grow * kH + col] = h2;
            unsigned hv, lv;
            split2(h2, hv, lv);
            const int byte = lr * 512 + (((col >> 3) ^ (lr & 7)) << 4) + (col & 7) * 2;
            *(unsigned short*)((char*)Hh + byte) = (unsigned short)hv;
            *(unsigned short*)((char*)Hl + byte) = (unsigned short)lv;
        }
    }
    __syncthreads();

    // ---- GEMM2 per nf: U,V = hnew x Wuv^T  (N=512)
    #pragma unroll
    for (int nf = 0; nf < 8; ++nf) {
        const int col = w * 128 + nf * 16 + mrow;
        const unsigned short* Wh_ = Wuvh + (size_t)col * kH + mq * 8;
        const unsigned short* Wl_ = Wuvl + (size_t)col * kH + mq * 8;
        f32x4 aUV = {0.f, 0.f, 0.f, 0.f};
        short8 rh[2], rl[2];
        rh[0] = *(const short8*)(Wh_); rl[0] = *(const short8*)(Wl_);
        #pragma unroll
        for (int kt = 0; kt < 8; ++kt) {
            const int cur = kt & 1;
            if (kt + 1 < 8) {
                rh[cur^1] = *(const short8*)(Wh_ + (kt + 1) * 32);
                rl[cur^1] = *(const short8*)(Wl_ + (kt + 1) * 32);
            }
            const int g = kt * 4 + mq;
            const int byte = mrow * 512 + ((g ^ (mrow & 7)) << 4);
            short8 zh = *(const short8*)((const char*)Hh + byte);
            short8 zl = *(const short8*)((const char*)Hl + byte);
            MFMA3(aUV, zh, zl, rh[cur], rl[cur]);
        }
        #pragma unroll
        for (int reg = 0; reg < 4; ++reg) {
            const int grow = m0 + mq * 4 + reg;
            const float v = aUV[reg];
            if (col < 256) Uo[(size_t)grow * kH + col] = v;
            else Vo[(size_t)grow * kH + col - 256] = v;
        }
    }
}

// ---------------- batched output MLP (split-bf16 MFMA) ----------------
__global__ __launch_bounds__(256, 2)
void out_kernel(const float* __restrict__ hist,
                const unsigned short* __restrict__ F1h, const unsigned short* __restrict__ F1l,
                const unsigned short* __restrict__ F2h, const unsigned short* __restrict__ F2l,
                const unsigned short* __restrict__ F3h, const unsigned short* __restrict__ F3l,
                const float* __restrict__ fc1b, const float* __restrict__ fc2b,
                const float* __restrict__ fc3b, float* __restrict__ out) {
    __shared__ __align__(16) unsigned short Ah[32 * 256], Al[32 * 256];  // 32 KiB
    __shared__ __align__(16) unsigned short Bh[32 * 256], Bl[32 * 256];  // 32 KiB
    const int m0 = blockIdx.x * 32;
    const int tid = threadIdx.x;

    #pragma unroll
    for (int it = 0; it < 4; ++it) {
        const int c = tid + it * 256;
        const int r = c >> 5, o = c & 31;
        const float* ap = hist + (size_t)(m0 + r) * kH + o * 8;
        float x[8];
        *(float4*)&x[0] = ((const float4*)ap)[0];
        *(float4*)&x[4] = ((const float4*)ap)[1];
        uint4 ph, pl;
        split8(x, ph, pl);
        const int byte = r * 512 + ((o << 4) ^ ((r & 7) << 4));
        *(uint4*)((char*)Ah + byte) = ph;
        *(uint4*)((char*)Al + byte) = pl;
    }
    __syncthreads();

    const int lane = tid & 63, w = tid >> 6;
    const int mrow = lane & 15, mq = lane >> 4;

    #define LAYER(SRCH, SRCL, WH, WL, BIAS, DSTH, DSTL)                         \
    {                                                                           \
        f32x4 acc[2][4];                                                        \
        _Pragma("unroll")                                                       \
        for (int m = 0; m < 2; ++m)                                             \
            _Pragma("unroll")                                                   \
            for (int nf = 0; nf < 4; ++nf) acc[m][nf] = (f32x4){0.f,0.f,0.f,0.f};\
        const unsigned short* wbh = WH + (size_t)(w * 64 + mrow) * kH + mq * 8; \
        const unsigned short* wbl = WL + (size_t)(w * 64 + mrow) * kH + mq * 8; \
        short8 rbh[2][4], rbl[2][4];                                            \
        _Pragma("unroll")                                                       \
        for (int nf = 0; nf < 4; ++nf) {                                        \
            rbh[0][nf] = *(const short8*)(wbh + nf * 16 * kH);                  \
            rbl[0][nf] = *(const short8*)(wbl + nf * 16 * kH);                  \
        }                                                                       \
        _Pragma("unroll")                                                       \
        for (int kt = 0; kt < 8; ++kt) {                                        \
            const int cur = kt & 1;                                             \
            if (kt + 1 < 8) {                                                   \
                _Pragma("unroll")                                               \
                for (int nf = 0; nf < 4; ++nf) {                                \
                    rbh[cur^1][nf] = *(const short8*)(wbh + nf * 16 * kH + (kt+1) * 32); \
                    rbl[cur^1][nf] = *(const short8*)(wbl + nf * 16 * kH + (kt+1) * 32); \
                }                                                               \
            }                                                                   \
            const int k0 = kt * 32;                                            \
            short8 zh[2], zl[2];                                                \
            _Pragma("unroll")                                                   \
            for (int m = 0; m < 2; ++m) {                                       \
                const int r = m * 16 + mrow;                                    \
                const int byte = r * 512 + (((k0 + mq * 8) * 2) ^ ((r & 7) << 4)); \
                zh[m] = *(const short8*)((const char*)SRCH + byte);             \
                zl[m] = *(const short8*)((const char*)SRCL + byte);             \
            }                                                                   \
            _Pragma("unroll")                                                   \
            for (int m = 0; m < 2; ++m)                                         \
                _Pragma("unroll")                                               \
                for (int nf = 0; nf < 4; ++nf) {                                \
                    MFMA3(acc[m][nf], zh[m], zl[m], rbh[cur][nf], rbl[cur][nf]); \
                }                                                               \
        }                                                                       \
        _Pragma("unroll")                                                       \
        for (int m = 0; m < 2; ++m)                                             \
            _Pragma("unroll")                                                   \
            for (int nf = 0; nf < 4; ++nf) {                                    \
                const int col = w * 64 + nf * 16 + mrow;                        \
                const float bv = BIAS[col];                                     \
                _Pragma("unroll")                                               \
                for (int reg = 0; reg < 4; ++reg) {                             \
                    const int lr = m * 16 + mq * 4 + reg;                       \
                    float v = fmaxf(acc[m][nf][reg] + bv, 0.f);                 \
                    unsigned hv, lv;                                            \
                    split2(v, hv, lv);                                          \
                    const int byte = lr * 512 + (((col >> 3) ^ (lr & 7)) << 4) + (col & 7) * 2; \
                    *(unsigned short*)((char*)DSTH + byte) = (unsigned short)hv; \
                    *(unsigned short*)((char*)DSTL + byte) = (unsigned short)lv; \
                }                                                               \
            }                                                                   \
        __syncthreads();                                                        \
    }

    LAYER(Ah, Al, F1h, F1l, fc1b, Bh, Bl)
    LAYER(Bh, Bl, F2h, F2l, fc2b, Ah, Al)

    // fc3: N=64, per wave 1 frag of 16 cols
    {
        f32x4 acc[2];
        acc[0] = (f32x4){0.f, 0.f, 0.f, 0.f};
        acc[1] = (f32x4){0.f, 0.f, 0.f, 0.f};
        const int row = w * 16 + mrow;
        const unsigned short* wbh = F3h + (size_t)row * kH + mq * 8;
        const unsigned short* wbl = F3l + (size_t)row * kH + mq * 8;
        short8 rh[2], rl[2];
        rh[0] = *(const short8*)(wbh); rl[0] = *(const short8*)(wbl);
        #pragma unroll
        for (int kt = 0; kt < 8; ++kt) {
            const int cur = kt & 1;
            if (kt + 1 < 8) {
                rh[cur^1] = *(const short8*)(wbh + (kt + 1) * 32);
                rl[cur^1] = *(const short8*)(wbl + (kt + 1) * 32);
            }
            const int k0 = kt * 32;
            short8 zh[2], zl[2];
            #pragma unroll
            for (int m = 0; m < 2; ++m) {
                const int r = m * 16 + mrow;
                const int byte = r * 512 + (((k0 + mq * 8) * 2) ^ ((r & 7) << 4));
                zh[m] = *(const short8*)((const char*)Ah + byte);
                zl[m] = *(const short8*)((const char*)Al + byte);
            }
            #pragma unroll
            for (int m = 0; m < 2; ++m) { MFMA3(acc[m], zh[m], zl[m], rh[cur], rl[cur]); }
        }
        const int col = w * 16 + mrow;
        const float bv = fc3b[col];
        #pragma unroll
        for (int m = 0; m < 2; ++m)
            #pragma unroll
            for (int reg = 0; reg < 4; ++reg) {
                const int grow = m0 + m * 16 + mq * 4 + reg;
                const int t = grow >> 10, bn = grow & 1023, b = bn >> 6, n = bn & 63;
                out[(((size_t)b * kTS + t) * kN + n) * kDout + col] = acc[m][reg] + bv;
            }
    }
    #undef LAYER
}

extern "C" void kernel_launch(void* const* d_in, const int* in_sizes, int n_in,
                              void* d_out, int out_size, void* d_ws, size_t ws_size,
                              hipStream_t stream) {
    const float* inputs    = (const float*)d_in[0];
    const float* rel_rec   = (const float*)d_in[1];
    const float* rel_send  = (const float*)d_in[2];
    const float* rel_types = (const float*)d_in[3];
    const float* W1  = (const float*)d_in[4];  const float* b1  = (const float*)d_in[5];
    const float* W2  = (const float*)d_in[6];  const float* b2  = (const float*)d_in[7];
    const float* Wir = (const float*)d_in[8];  const float* bir = (const float*)d_in[9];
    const float* Whr = (const float*)d_in[10]; const float* bhr = (const float*)d_in[11];
    const float* Wii = (const float*)d_in[12]; const float* bii = (const float*)d_in[13];
    const float* Whi = (const float*)d_in[14]; const float* bhi = (const float*)d_in[15];
    const float* Win = (const float*)d_in[16]; const float* bin_ = (const float*)d_in[17];
    const float* Whn = (const float*)d_in[18]; const float* bhn = (const float*)d_in[19];
    const float* fc1w = (const float*)d_in[20]; const float* fc1b = (const float*)d_in[21];
    const float* fc2w = (const float*)d_in[22]; const float* fc2b = (const float*)d_in[23];
    const float* fc3w = (const float*)d_in[24]; const float* fc3b = (const float*)d_in[25];
    float* out = (float*)d_out;

    char* w = (char*)d_ws;
    auto take = [&](size_t bytes) { char* p = w; w += (bytes + 255) & ~(size_t)255; return p; };
    int* edge_at = (int*)take(kN * kN * 4);
    float* ts = (float*)take(kB * kE * 4);
    unsigned short* W2h = (unsigned short*)take(kH * kH * 2);
    unsigned short* W2l = (unsigned short*)take(kH * kH * 2);
    unsigned short* Wrih = (unsigned short*)take(512 * 320 * 2);
    unsigned short* Wril = (unsigned short*)take(512 * 320 * 2);
    unsigned short* Wnhh = (unsigned short*)take(kH * kH * 2);
    unsigned short* Wnhl = (unsigned short*)take(kH * kH * 2);
    unsigned short* Wnxh = (unsigned short*)take(kH * kDin * 2);
    unsigned short* Wnxl = (unsigned short*)take(kH * kDin * 2);
    unsigned short* Wuvh = (unsigned short*)take(512 * 256 * 2);
    unsigned short* Wuvl = (unsigned short*)take(512 * 256 * 2);
    unsigned short* F1h = (unsigned short*)take(kH * kH * 2);
    unsigned short* F1l = (unsigned short*)take(kH * kH * 2);
    unsigned short* F2h = (unsigned short*)take(kH * kH * 2);
    unsigned short* F2l = (unsigned short*)take(kH * kH * 2);
    unsigned short* F3h = (unsigned short*)take(kDout * kH * 2);
    unsigned short* F3l = (unsigned short*)take(kDout * kH * 2);
    float* bri = (float*)take(512 * 4);
    float* U = (float*)take((size_t)kBN * kH * 4);
    float* V = (float*)take((size_t)kBN * kH * 4);
    float* agg = (float*)take((size_t)kBN * kH * 4);
    float* hh = (float*)w;   // (kTS+1) * kBN * kH floats (~42 MiB)

    hipMemsetAsync(edge_at, 0xFF, kN * kN * 4, stream);
    setup_kernel<<<640, 256, 0, stream>>>(
        rel_rec, rel_send, rel_types, W2, Whr, Whi, Whn, Wir, Wii, Win, W1,
        bir, bhr, bii, bhi, fc1w, fc2w, fc3w,
        edge_at, ts, W2h, W2l, Wrih, Wril, Wnhh, Wnhl, Wnxh, Wnxl,
        Wuvh, Wuvl, F1h, F1l, F2h, F2l, F3h, F3l, bri);
    hipMemsetAsync(U, 0, (size_t)kBN * kH * 4, stream);
    hipMemsetAsync(V, 0, (size_t)kBN * kH * 4, stream);
    hipMemsetAsync(hh, 0, (size_t)kBN * kH * 4, stream);   // h_0 = 0

    for (int t = 0; t < kTS; ++t) {
        edge_kernel<<<kBN, 256, 0, stream>>>(U, V, W2h, W2l, b1, b2, ts, edge_at, agg);
        gru_kernel<<<kBN / 16, 256, 0, stream>>>(
            hh + (size_t)t * kBN * kH, agg, inputs, t,
            Wrih, Wril, Wnhh, Wnhl, Wnxh, Wnxl, Wuvh, Wuvl, bri, bhn, bin_,
            hh + (size_t)(t + 1) * kBN * kH, U, V);
    }
    out_kernel<<<kTS * kBN / 32, 256, 0, stream>>>(
        hh + (size_t)kBN * kH, F1h, F1l, F2h, F2l, F3h, F3l,
        fc1b, fc2b, fc3b, out);
}

// Round 6
// 2093.232 us; speedup vs baseline: 1.9228x; 1.7512x over previous
//
#include <hip/hip_runtime.h>
#include <math.h>

// GRUDecoder (NRI decoder) on MI355X — round 6: single-fp16 MFMA everywhere.
// Rationale: round-2 anchor (bf16 ops -> 1.27e-2 absmax) scales to fp16 as
// eps 2^-9 -> 2^-12, predicting ~2-3.5e-3 < 5.5e-3 threshold. 3x fewer MFMA,
// half the LDS (edge: 4 blocks/CU), half the staging VALU vs split-bf16.

namespace {
constexpr int kB = 16, kT = 40, kTS = 39, kN = 64, kDin = 64, kH = 256;
constexpr int kE = kN * (kN - 1);   // 4032
constexpr int kBN = kB * kN;        // 1024
constexpr int kDout = 64;
}

typedef _Float16 half8 __attribute__((ext_vector_type(8)));
typedef float f32x4 __attribute__((ext_vector_type(4)));

__device__ __forceinline__ float sigm(float x) { return 1.f / (1.f + expf(-x)); }

__device__ __forceinline__ unsigned short f2h(float x) {
    _Float16 h = (_Float16)x;          // v_cvt_f16_f32, RNE
    return __builtin_bit_cast(unsigned short, h);
}

// pack 8 floats -> uint4 of 8 fp16
__device__ __forceinline__ uint4 pack8h(const float* x) {
    unsigned us[8];
    #pragma unroll
    for (int q = 0; q < 8; ++q) us[q] = f2h(x[q]);
    uint4 p;
    p.x = us[0] | (us[1] << 16); p.y = us[2] | (us[3] << 16);
    p.z = us[4] | (us[5] << 16); p.w = us[6] | (us[7] << 16);
    return p;
}

// ---------------- setup: edge table, type sums, all weights -> fp16 ---------
__global__ void setup_kernel(
    const float* __restrict__ rel_rec, const float* __restrict__ rel_send,
    const float* __restrict__ rel_types, const float* __restrict__ W2,
    const float* __restrict__ Whr, const float* __restrict__ Whi,
    const float* __restrict__ Whn, const float* __restrict__ Wir,
    const float* __restrict__ Wii, const float* __restrict__ Win,
    const float* __restrict__ W1,
    const float* __restrict__ bir, const float* __restrict__ bhr,
    const float* __restrict__ bii, const float* __restrict__ bhi,
    const float* __restrict__ fc1w, const float* __restrict__ fc2w,
    const float* __restrict__ fc3w,
    int* __restrict__ edge_at, float* __restrict__ ts,
    unsigned short* __restrict__ W2f,
    unsigned short* __restrict__ Wri,
    unsigned short* __restrict__ Wnh,
    unsigned short* __restrict__ Wnx,
    unsigned short* __restrict__ Wuv,
    unsigned short* __restrict__ F1, unsigned short* __restrict__ F2,
    unsigned short* __restrict__ F3,
    float* __restrict__ bri) {
    int idx = blockIdx.x * 256 + threadIdx.x;
    if (idx < kE) {
        int si = 0, ri = 0;
        for (int n = 0; n < kN; ++n) {
            if (rel_send[idx * kN + n] > 0.5f) si = n;
            if (rel_rec[idx * kN + n] > 0.5f) ri = n;
        }
        edge_at[ri * kN + si] = idx;
    }
    if (idx < kB * kE) ts[idx] = rel_types[2 * idx] + rel_types[2 * idx + 1];
    if (idx < kH * kH) {
        W2f[idx] = f2h(W2[idx]);
        Wnh[idx] = f2h(Whn[idx]);
        F1[idx] = f2h(fc1w[idx]);
        F2[idx] = f2h(fc2w[idx]);
    }
    if (idx < 512 * 320) {  // Wri = [[Whr|Wir],[Whi|Wii]]  rows x K=320
        int row = idx / 320, k = idx - row * 320;
        float v;
        if (row < 256) v = (k < kH) ? Whr[row * kH + k] : Wir[row * kDin + k - kH];
        else { int o = row - 256; v = (k < kH) ? Whi[o * kH + k] : Wii[o * kDin + k - kH]; }
        Wri[idx] = f2h(v);
    }
    if (idx < kH * kDin) Wnx[idx] = f2h(Win[idx]);
    if (idx < 512 * 256) {  // Wuv: row<256 -> U (W1 cols 0..255), else V
        int row = idx >> 8, k = idx & 255;
        float v = (row < 256) ? W1[row * 512 + k] : W1[(row - 256) * 512 + 256 + k];
        Wuv[idx] = f2h(v);
    }
    if (idx < kDout * kH) F3[idx] = f2h(fc3w[idx]);
    if (idx < 256) bri[idx] = bir[idx] + bhr[idx];
    else if (idx < 512) bri[idx] = bii[idx - 256] + bhi[idx - 256];
}

// ---------------- per-step: edge messages + aggregation (fp16 MFMA) --------
// One block per (b, receiver j). 256 thr = 4 waves; 33 KiB LDS -> 4 blocks/CU.
__global__ __launch_bounds__(256, 4)
void edge_kernel(const float* __restrict__ U, const float* __restrict__ V,
                 const unsigned short* __restrict__ W2f,
                 const float* __restrict__ b1, const float* __restrict__ b2,
                 const float* __restrict__ ts, const int* __restrict__ edge_at,
                 float* __restrict__ agg) {
    __shared__ __align__(16) unsigned short h1[kN * kH];  // 32 KiB, swizzled
    __shared__ float vjb[kH];
    __shared__ float tss[kN];
    const int blk = blockIdx.x, b = blk >> 6, j = blk & 63;
    const int tid = threadIdx.x;

    if (tid < kN) {
        int e = edge_at[j * kN + tid];
        tss[tid] = (e < 0) ? 0.f : ts[b * kE + e];
    }
    vjb[tid] = V[(b * kN + j) * kH + tid] + b1[tid];
    __syncthreads();

    // ---- build h1 = relu(U_i + vjb) as fp16, swizzle byte ^= (row&7)<<4
    {
        const int o = tid & 31, i0 = tid >> 5;   // k-octet o, starting row
        const int k0 = o * 8;
        const float4 vj0 = *(const float4*)&vjb[k0];
        const float4 vj1 = *(const float4*)&vjb[k0 + 4];
        #pragma unroll
        for (int p = 0; p < 8; ++p) {
            const int i = i0 + 8 * p;
            const float4* up = (const float4*)(U + (b * kN + i) * kH + k0);
            float4 f0 = up[0], f1 = up[1];
            float x[8] = {f0.x + vj0.x, f0.y + vj0.y, f0.z + vj0.z, f0.w + vj0.w,
                          f1.x + vj1.x, f1.y + vj1.y, f1.z + vj1.z, f1.w + vj1.w};
            #pragma unroll
            for (int q = 0; q < 8; ++q) x[q] = (i == j) ? 0.f : fmaxf(x[q], 0.f);
            const int byte = i * 512 + ((k0 * 2) ^ ((i & 7) << 4));
            *(uint4*)((char*)h1 + byte) = pack8h(x);
        }
    }
    __syncthreads();

    // ---- MFMA: out[i][col] = sum_k h1[i][k] * W2[col][k]
    const int lane = tid & 63, w = tid >> 6;
    const int mrow = lane & 15, mq = lane >> 4;
    f32x4 acc[4][4];
    #pragma unroll
    for (int mf = 0; mf < 4; ++mf)
        #pragma unroll
        for (int nf = 0; nf < 4; ++nf) acc[mf][nf] = (f32x4){0.f, 0.f, 0.f, 0.f};

    const unsigned short* Wp = W2f + (size_t)(w * 64 + mrow) * kH + mq * 8;
    #pragma unroll
    for (int kt = 0; kt < 8; ++kt) {
        const int k0 = kt * 32;
        half8 a[4], bb[4];
        #pragma unroll
        for (int mf = 0; mf < 4; ++mf) {
            const int r = mf * 16 + mrow;
            const int byte = r * 512 + (((k0 + mq * 8) * 2) ^ ((r & 7) << 4));
            a[mf] = *(const half8*)((const char*)h1 + byte);
        }
        #pragma unroll
        for (int nf = 0; nf < 4; ++nf)
            bb[nf] = *(const half8*)(Wp + nf * 16 * kH + k0);
        #pragma unroll
        for (int mf = 0; mf < 4; ++mf)
            #pragma unroll
            for (int nf = 0; nf < 4; ++nf)
                acc[mf][nf] = __builtin_amdgcn_mfma_f32_16x16x32_f16(
                    a[mf], bb[nf], acc[mf][nf], 0, 0, 0);
    }

    // ---- epilogue: relu(+b2), ts-weight, reduce over senders (M)
    float tsr[16];
    #pragma unroll
    for (int mf = 0; mf < 4; ++mf)
        #pragma unroll
        for (int r = 0; r < 4; ++r)
            tsr[mf * 4 + r] = tss[mf * 16 + mq * 4 + r];   // D row = (lane>>4)*4+r
    #pragma unroll
    for (int nf = 0; nf < 4; ++nf) {
        const int col = w * 64 + nf * 16 + mrow;
        const float bv = b2[col];
        float s = 0.f;
        #pragma unroll
        for (int mf = 0; mf < 4; ++mf)
            #pragma unroll
            for (int r = 0; r < 4; ++r)
                s += tsr[mf * 4 + r] * fmaxf(acc[mf][nf][r] + bv, 0.f);
        s += __shfl_xor(s, 16);
        s += __shfl_xor(s, 32);
        if (lane < 16) agg[(b * kN + j) * kH + col] = s;
    }
}

// ---------------- per-step: GRU gates + hnew + U,V (fp16 MFMA) -------------
// 64 blocks x 256 thr; block owns 16 rows. 1 block/CU -> keep ring-2 prefetch.
__global__ __launch_bounds__(256, 1)
void gru_kernel(const float* __restrict__ hprev, const float* __restrict__ agg,
                const float* __restrict__ inputs, int t,
                const unsigned short* __restrict__ Wri,
                const unsigned short* __restrict__ Wnh,
                const unsigned short* __restrict__ Wnx,
                const unsigned short* __restrict__ Wuv,
                const float* __restrict__ bri, const float* __restrict__ bhn,
                const float* __restrict__ bin_,
                float* __restrict__ hnew, float* __restrict__ Uo,
                float* __restrict__ Vo) {
    __shared__ __align__(16) unsigned short Zf[16 * 320];  // 10 KiB
    __shared__ __align__(16) unsigned short Hf[16 * 256];  // 8 KiB
    const int m0 = blockIdx.x * 16;
    const int tid = threadIdx.x;

    // ---- stage Z = [agg | x]: 16 rows x 40 octets, swizzled rows of 640 B
    for (int c = tid; c < 16 * 40; c += 256) {
        const int r = c / 40, g = c - r * 40;
        float x[8];
        if (g < 32) {
            const float* ap = agg + (size_t)(m0 + r) * kH + g * 8;
            *(float4*)&x[0] = ((const float4*)ap)[0];
            *(float4*)&x[4] = ((const float4*)ap)[1];
        } else {
            const int grow = m0 + r, b = grow >> 6, n = grow & 63;
            const float* xp = inputs + ((size_t)(b * kT + t) * kN + n) * kDin + (g - 32) * 8;
            *(float4*)&x[0] = ((const float4*)xp)[0];
            *(float4*)&x[4] = ((const float4*)xp)[1];
        }
        const int byte = r * 640 + ((g ^ (r & 7)) << 4);
        *(uint4*)((char*)Zf + byte) = pack8h(x);
    }
    __syncthreads();

    const int lane = tid & 63, w = tid >> 6;
    const int mrow = lane & 15, mq = lane >> 4;

    // ---- GEMM1 per nf: r,i (K=320), n (h-side K=256, x-side K=64)
    #pragma unroll
    for (int nf = 0; nf < 4; ++nf) {
        const int col = w * 64 + nf * 16 + mrow;
        const unsigned short* WR = Wri + (size_t)col * 320 + mq * 8;
        const unsigned short* WI = Wri + (size_t)(256 + col) * 320 + mq * 8;
        const unsigned short* WNh = Wnh + (size_t)col * kH + mq * 8;
        const unsigned short* WNx = Wnx + (size_t)col * kDin + mq * 8;

        f32x4 aR = {0.f,0.f,0.f,0.f}, aI = {0.f,0.f,0.f,0.f};
        f32x4 aNH = {0.f,0.f,0.f,0.f}, aNX = {0.f,0.f,0.f,0.f};

        half8 rw[2][3];   // [slot][gate: r,i,n]
        rw[0][0] = *(const half8*)(WR);
        rw[0][1] = *(const half8*)(WI);
        rw[0][2] = *(const half8*)(WNh);
        #pragma unroll
        for (int kt = 0; kt < 10; ++kt) {
            const int cur = kt & 1;
            if (kt + 1 < 10) {
                const int k1 = (kt + 1) * 32;
                rw[cur^1][0] = *(const half8*)(WR + k1);
                rw[cur^1][1] = *(const half8*)(WI + k1);
                if (kt + 1 < 8) rw[cur^1][2] = *(const half8*)(WNh + k1);
                else            rw[cur^1][2] = *(const half8*)(WNx + (k1 - 256));
            }
            const int g = kt * 4 + mq;
            const int byte = mrow * 640 + ((g ^ (mrow & 7)) << 4);
            half8 zf = *(const half8*)((const char*)Zf + byte);
            aR = __builtin_amdgcn_mfma_f32_16x16x32_f16(zf, rw[cur][0], aR, 0, 0, 0);
            aI = __builtin_amdgcn_mfma_f32_16x16x32_f16(zf, rw[cur][1], aI, 0, 0, 0);
            if (kt < 8) aNH = __builtin_amdgcn_mfma_f32_16x16x32_f16(zf, rw[cur][2], aNH, 0, 0, 0);
            else        aNX = __builtin_amdgcn_mfma_f32_16x16x32_f16(zf, rw[cur][2], aNX, 0, 0, 0);
        }

        // gate elementwise for this nf's 16 cols
        const float brv = bri[col], biv = bri[256 + col];
        const float bhnv = bhn[col], binv = bin_[col];
        #pragma unroll
        for (int reg = 0; reg < 4; ++reg) {
            const int lr = mq * 4 + reg;
            const int grow = m0 + lr;
            float rg = sigm(aR[reg] + brv);
            float ig = sigm(aI[reg] + biv);
            float ng = tanhf(aNX[reg] + binv + rg * (aNH[reg] + bhnv));
            float h2 = (1.f - ig) * ng + ig * hprev[(size_t)grow * kH + col];
            hnew[(size_t)grow * kH + col] = h2;
            const int byte = lr * 512 + (((col >> 3) ^ (lr & 7)) << 4) + (col & 7) * 2;
            *(unsigned short*)((char*)Hf + byte) = f2h(h2);
        }
    }
    __syncthreads();

    // ---- GEMM2 per nf: U,V = hnew x Wuv^T  (N=512)
    #pragma unroll
    for (int nf = 0; nf < 8; ++nf) {
        const int col = w * 128 + nf * 16 + mrow;
        const unsigned short* Wp = Wuv + (size_t)col * kH + mq * 8;
        f32x4 aUV = {0.f, 0.f, 0.f, 0.f};
        half8 rw[2];
        rw[0] = *(const half8*)(Wp);
        #pragma unroll
        for (int kt = 0; kt < 8; ++kt) {
            const int cur = kt & 1;
            if (kt + 1 < 8) rw[cur^1] = *(const half8*)(Wp + (kt + 1) * 32);
            const int g = kt * 4 + mq;
            const int byte = mrow * 512 + ((g ^ (mrow & 7)) << 4);
            half8 zf = *(const half8*)((const char*)Hf + byte);
            aUV = __builtin_amdgcn_mfma_f32_16x16x32_f16(zf, rw[cur], aUV, 0, 0, 0);
        }
        #pragma unroll
        for (int reg = 0; reg < 4; ++reg) {
            const int grow = m0 + mq * 4 + reg;
            const float v = aUV[reg];
            if (col < 256) Uo[(size_t)grow * kH + col] = v;
            else Vo[(size_t)grow * kH + col - 256] = v;
        }
    }
}

// ---------------- batched output MLP (fp16 MFMA) ----------------
// 1248 blocks x 256 thr; 32 KiB LDS -> 4 blocks/CU.
__global__ __launch_bounds__(256, 4)
void out_kernel(const float* __restrict__ hist,
                const unsigned short* __restrict__ F1,
                const unsigned short* __restrict__ F2,
                const unsigned short* __restrict__ F3,
                const float* __restrict__ fc1b, const float* __restrict__ fc2b,
                const float* __restrict__ fc3b, float* __restrict__ out) {
    __shared__ __align__(16) unsigned short Af[32 * 256];  // 16 KiB
    __shared__ __align__(16) unsigned short Bf[32 * 256];  // 16 KiB
    const int m0 = blockIdx.x * 32;
    const int tid = threadIdx.x;

    #pragma unroll
    for (int it = 0; it < 4; ++it) {
        const int c = tid + it * 256;
        const int r = c >> 5, o = c & 31;
        const float* ap = hist + (size_t)(m0 + r) * kH + o * 8;
        float x[8];
        *(float4*)&x[0] = ((const float4*)ap)[0];
        *(float4*)&x[4] = ((const float4*)ap)[1];
        const int byte = r * 512 + ((o << 4) ^ ((r & 7) << 4));
        *(uint4*)((char*)Af + byte) = pack8h(x);
    }
    __syncthreads();

    const int lane = tid & 63, w = tid >> 6;
    const int mrow = lane & 15, mq = lane >> 4;

    #define LAYER(SRC, WW, BIAS, DST)                                           \
    {                                                                           \
        f32x4 acc[2][4];                                                        \
        _Pragma("unroll")                                                       \
        for (int m = 0; m < 2; ++m)                                             \
            _Pragma("unroll")                                                   \
            for (int nf = 0; nf < 4; ++nf) acc[m][nf] = (f32x4){0.f,0.f,0.f,0.f};\
        const unsigned short* wb = WW + (size_t)(w * 64 + mrow) * kH + mq * 8;  \
        _Pragma("unroll")                                                       \
        for (int kt = 0; kt < 8; ++kt) {                                        \
            const int k0 = kt * 32;                                             \
            half8 zf[2], bb[4];                                                 \
            _Pragma("unroll")                                                   \
            for (int m = 0; m < 2; ++m) {                                       \
                const int r = m * 16 + mrow;                                    \
                const int byte = r * 512 + (((k0 + mq * 8) * 2) ^ ((r & 7) << 4)); \
                zf[m] = *(const half8*)((const char*)SRC + byte);               \
            }                                                                   \
            _Pragma("unroll")                                                   \
            for (int nf = 0; nf < 4; ++nf)                                      \
                bb[nf] = *(const half8*)(wb + nf * 16 * kH + k0);               \
            _Pragma("unroll")                                                   \
            for (int m = 0; m < 2; ++m)                                         \
                _Pragma("unroll")                                               \
                for (int nf = 0; nf < 4; ++nf)                                  \
                    acc[m][nf] = __builtin_amdgcn_mfma_f32_16x16x32_f16(        \
                        zf[m], bb[nf], acc[m][nf], 0, 0, 0);                    \
        }                                                                       \
        _Pragma("unroll")                                                       \
        for (int m = 0; m < 2; ++m)                                             \
            _Pragma("unroll")                                                   \
            for (int nf = 0; nf < 4; ++nf) {                                    \
                const int col = w * 64 + nf * 16 + mrow;                        \
                const float bv = BIAS[col];                                     \
                _Pragma("unroll")                                               \
                for (int reg = 0; reg < 4; ++reg) {                             \
                    const int lr = m * 16 + mq * 4 + reg;                       \
                    float v = fmaxf(acc[m][nf][reg] + bv, 0.f);                 \
                    const int byte = lr * 512 + (((col >> 3) ^ (lr & 7)) << 4) + (col & 7) * 2; \
                    *(unsigned short*)((char*)DST + byte) = f2h(v);             \
                }                                                               \
            }                                                                   \
        __syncthreads();                                                        \
    }

    LAYER(Af, F1, fc1b, Bf)
    LAYER(Bf, F2, fc2b, Af)

    // fc3: N=64, per wave 1 frag of 16 cols
    {
        f32x4 acc[2];
        acc[0] = (f32x4){0.f, 0.f, 0.f, 0.f};
        acc[1] = (f32x4){0.f, 0.f, 0.f, 0.f};
        const int row = w * 16 + mrow;
        const unsigned short* wb = F3 + (size_t)row * kH + mq * 8;
        #pragma unroll
        for (int kt = 0; kt < 8; ++kt) {
            const int k0 = kt * 32;
            half8 zf[2];
            #pragma unroll
            for (int m = 0; m < 2; ++m) {
                const int r = m * 16 + mrow;
                const int byte = r * 512 + (((k0 + mq * 8) * 2) ^ ((r & 7) << 4));
                zf[m] = *(const half8*)((const char*)Af + byte);
            }
            half8 bb = *(const half8*)(wb + k0);
            #pragma unroll
            for (int m = 0; m < 2; ++m)
                acc[m] = __builtin_amdgcn_mfma_f32_16x16x32_f16(zf[m], bb, acc[m], 0, 0, 0);
        }
        const int col = w * 16 + mrow;
        const float bv = fc3b[col];
        #pragma unroll
        for (int m = 0; m < 2; ++m)
            #pragma unroll
            for (int reg = 0; reg < 4; ++reg) {
                const int grow = m0 + m * 16 + mq * 4 + reg;
                const int t = grow >> 10, bn = grow & 1023, b = bn >> 6, n = bn & 63;
                out[(((size_t)b * kTS + t) * kN + n) * kDout + col] = acc[m][reg] + bv;
            }
    }
    #undef LAYER
}

extern "C" void kernel_launch(void* const* d_in, const int* in_sizes, int n_in,
                              void* d_out, int out_size, void* d_ws, size_t ws_size,
                              hipStream_t stream) {
    const float* inputs    = (const float*)d_in[0];
    const float* rel_rec   = (const float*)d_in[1];
    const float* rel_send  = (const float*)d_in[2];
    const float* rel_types = (const float*)d_in[3];
    const float* W1  = (const float*)d_in[4];  const float* b1  = (const float*)d_in[5];
    const float* W2  = (const float*)d_in[6];  const float* b2  = (const float*)d_in[7];
    const float* Wir = (const float*)d_in[8];  const float* bir = (const float*)d_in[9];
    const float* Whr = (const float*)d_in[10]; const float* bhr = (const float*)d_in[11];
    const float* Wii = (const float*)d_in[12]; const float* bii = (const float*)d_in[13];
    const float* Whi = (const float*)d_in[14]; const float* bhi = (const float*)d_in[15];
    const float* Win = (const float*)d_in[16]; const float* bin_ = (const float*)d_in[17];
    const float* Whn = (const float*)d_in[18]; const float* bhn = (const float*)d_in[19];
    const float* fc1w = (const float*)d_in[20]; const float* fc1b = (const float*)d_in[21];
    const float* fc2w = (const float*)d_in[22]; const float* fc2b = (const float*)d_in[23];
    const float* fc3w = (const float*)d_in[24]; const float* fc3b = (const float*)d_in[25];
    float* out = (float*)d_out;

    char* w = (char*)d_ws;
    auto take = [&](size_t bytes) { char* p = w; w += (bytes + 255) & ~(size_t)255; return p; };
    int* edge_at = (int*)take(kN * kN * 4);
    float* ts = (float*)take(kB * kE * 4);
    unsigned short* W2f = (unsigned short*)take(kH * kH * 2);
    unsigned short* Wri = (unsigned short*)take(512 * 320 * 2);
    unsigned short* Wnh = (unsigned short*)take(kH * kH * 2);
    unsigned short* Wnx = (unsigned short*)take(kH * kDin * 2);
    unsigned short* Wuv = (unsigned short*)take(512 * 256 * 2);
    unsigned short* F1 = (unsigned short*)take(kH * kH * 2);
    unsigned short* F2 = (unsigned short*)take(kH * kH * 2);
    unsigned short* F3 = (unsigned short*)take(kDout * kH * 2);
    float* bri = (float*)take(512 * 4);
    float* U = (float*)take((size_t)kBN * kH * 4);
    float* V = (float*)take((size_t)kBN * kH * 4);
    float* agg = (float*)take((size_t)kBN * kH * 4);
    float* hh = (float*)w;   // (kTS+1) * kBN * kH floats (~42 MiB)

    hipMemsetAsync(edge_at, 0xFF, kN * kN * 4, stream);
    setup_kernel<<<640, 256, 0, stream>>>(
        rel_rec, rel_send, rel_types, W2, Whr, Whi, Whn, Wir, Wii, Win, W1,
        bir, bhr, bii, bhi, fc1w, fc2w, fc3w,
        edge_at, ts, W2f, Wri, Wnh, Wnx, Wuv, F1, F2, F3, bri);
    hipMemsetAsync(U, 0, (size_t)kBN * kH * 4, stream);
    hipMemsetAsync(V, 0, (size_t)kBN * kH * 4, stream);
    hipMemsetAsync(hh, 0, (size_t)kBN * kH * 4, stream);   // h_0 = 0

    for (int t = 0; t < kTS; ++t) {
        edge_kernel<<<kBN, 256, 0, stream>>>(U, V, W2f, b1, b2, ts, edge_at, agg);
        gru_kernel<<<kBN / 16, 256, 0, stream>>>(
            hh + (size_t)t * kBN * kH, agg, inputs, t,
            Wri, Wnh, Wnx, Wuv, bri, bhn, bin_,
            hh + (size_t)(t + 1) * kBN * kH, U, V);
    }
    out_kernel<<<kTS * kBN / 32, 256, 0, stream>>>(
        hh + (size_t)kBN * kH, F1, F2, F3, fc1b, fc2b, fc3b, out);
}